// Round 6
// baseline (2523.971 us; speedup 1.0000x reference)
//
#include <hip/hip_runtime.h>
#include <hip/hip_bf16.h>
#include <math.h>

#define S 2048
#define D 2048
#define NH 16
#define NKV 8
#define HD 128
#define TOPK 40
#define EPSR 1e-6f
#define SCALEF 0.08838834764831845f

typedef __attribute__((ext_vector_type(8))) _Float16 f16x8;
typedef __attribute__((ext_vector_type(4))) _Float16 f16x4;
typedef __attribute__((ext_vector_type(4))) float f32x4;

#define GLB(p) ((const __attribute__((address_space(1))) void*)(p))
#define LDSP(p) ((__attribute__((address_space(3))) void*)(p))

// ============ fp32 GEMM, bit-identical accumulation (ascending-k fmaf), double-buffered
// LDS stride 133: store bank = (c*5+r) mod 32 -> conflict-free (2-way max).
// MODE 0: plain output slab; MODE 1: QKV scatter epilogue
template<int MODE>
__global__ __launch_bounds__(256) void fgemm(
    const float* __restrict__ A, int lda, size_t a_hs,
    const float* __restrict__ B0, const float* __restrict__ B1, const float* __restrict__ B2,
    int ldb, size_t b_hs, int b_div,
    float* __restrict__ C, int ldc, size_t c_hs,
    float* __restrict__ qb, float* __restrict__ kb, float* __restrict__ vb,
    int K, float alpha, int head0)
{
  __shared__ float As[2][32][133];
  __shared__ float Bs[2][32][133];
  int tid = threadIdx.x;
  int tx = tid & 15, ty = tid >> 4;
  int m0 = blockIdx.x * 128, n0 = blockIdx.y * 128;

  const float* Ag = A;
  const float* Bsrc;
  float* Cg = C;
  if (MODE == 0) {
    int h = head0 + blockIdx.z;
    Ag = A + (size_t)h * a_hs;
    Bsrc = B0 + (size_t)(h / b_div) * b_hs + (size_t)n0 * ldb;
    Cg = C + (size_t)blockIdx.z * c_hs;
  } else {
    if (n0 < 2048)      Bsrc = B0 + (size_t)n0 * ldb;
    else if (n0 < 3072) Bsrc = B1 + (size_t)(n0 - 2048) * ldb;
    else                Bsrc = B2 + (size_t)(n0 - 3072) * ldb;
  }

  float acc[8][8] = {};

  int r_[4], c_[4];
#pragma unroll
  for (int i = 0; i < 4; i++) {
    int f4 = tid + i * 256;
    r_[i] = f4 >> 3;
    c_[i] = (f4 & 7) * 4;
  }

  float4 avr[4], bvr[4];
#pragma unroll
  for (int i = 0; i < 4; i++) {
    avr[i] = *(const float4*)&Ag[(size_t)(m0 + r_[i]) * lda + c_[i]];
    bvr[i] = *(const float4*)&Bsrc[(size_t)r_[i] * ldb + c_[i]];
  }
#pragma unroll
  for (int i = 0; i < 4; i++) {
    As[0][c_[i] + 0][r_[i]] = avr[i].x; As[0][c_[i] + 1][r_[i]] = avr[i].y;
    As[0][c_[i] + 2][r_[i]] = avr[i].z; As[0][c_[i] + 3][r_[i]] = avr[i].w;
    Bs[0][c_[i] + 0][r_[i]] = bvr[i].x; Bs[0][c_[i] + 1][r_[i]] = bvr[i].y;
    Bs[0][c_[i] + 2][r_[i]] = bvr[i].z; Bs[0][c_[i] + 3][r_[i]] = bvr[i].w;
  }
  __syncthreads();

  int nIter = K >> 5;
  for (int it = 0; it < nIter; it++) {
    int buf = it & 1;
    bool more = (it + 1) < nIter;
    if (more) {
      int k0 = (it + 1) * 32;
#pragma unroll
      for (int i = 0; i < 4; i++) {
        avr[i] = *(const float4*)&Ag[(size_t)(m0 + r_[i]) * lda + k0 + c_[i]];
        bvr[i] = *(const float4*)&Bsrc[(size_t)r_[i] * ldb + k0 + c_[i]];
      }
    }
    const float (*Ab)[133] = As[buf];
    const float (*Bb)[133] = Bs[buf];
#pragma unroll 4
    for (int k = 0; k < 32; k++) {
      float a8[8], b8[8];
      *(float4*)&a8[0] = *(const float4*)&Ab[k][ty * 8];
      *(float4*)&a8[4] = *(const float4*)&Ab[k][ty * 8 + 4];
      *(float4*)&b8[0] = *(const float4*)&Bb[k][tx * 8];
      *(float4*)&b8[4] = *(const float4*)&Bb[k][tx * 8 + 4];
#pragma unroll
      for (int i = 0; i < 8; i++)
#pragma unroll
        for (int j = 0; j < 8; j++)
          acc[i][j] = fmaf(a8[i], b8[j], acc[i][j]);   // ascending-k chain: bit-exact
    }
    if (more) {
      int nb = buf ^ 1;
#pragma unroll
      for (int i = 0; i < 4; i++) {
        As[nb][c_[i] + 0][r_[i]] = avr[i].x; As[nb][c_[i] + 1][r_[i]] = avr[i].y;
        As[nb][c_[i] + 2][r_[i]] = avr[i].z; As[nb][c_[i] + 3][r_[i]] = avr[i].w;
        Bs[nb][c_[i] + 0][r_[i]] = bvr[i].x; Bs[nb][c_[i] + 1][r_[i]] = bvr[i].y;
        Bs[nb][c_[i] + 2][r_[i]] = bvr[i].z; Bs[nb][c_[i] + 3][r_[i]] = bvr[i].w;
      }
      __syncthreads();
    }
  }

#pragma unroll
  for (int i = 0; i < 8; i++) {
    int m = m0 + ty * 8 + i;
#pragma unroll
    for (int j = 0; j < 8; j++) {
      int n = n0 + tx * 8 + j;
      if (MODE == 0) {
        Cg[(size_t)m * ldc + n] = alpha * acc[i][j];
      } else {
        float val = acc[i][j];
        if (n < 2048) {
          qb[(size_t)(n >> 7) * (S * HD) + (size_t)m * HD + (n & 127)] = val;
        } else if (n < 3072) {
          int nn = n - 2048;
          kb[(size_t)(nn >> 7) * (S * HD) + (size_t)m * HD + (nn & 127)] = val;
        } else {
          int nn = n - 3072;
          vb[(size_t)(nn >> 7) * (S * HD) + (size_t)m * HD + (nn & 127)] = val;
        }
      }
    }
  }
}

// ============ round-1 rms_rope VERBATIM (bit-exact decision path) ============
__global__ __launch_bounds__(128) void rms_rope(
    float* __restrict__ qb, float* __restrict__ kb,
    const float* __restrict__ cosT, const float* __restrict__ sinT,
    const float* __restrict__ qw, const float* __restrict__ kw)
{
  int r = blockIdx.x;
  float* ptr; const float* w; int s;
  if (r < NH * S) { ptr = qb + (size_t)r * HD; w = qw; s = r & (S - 1); }
  else { int rr = r - NH * S; ptr = kb + (size_t)rr * HD; w = kw; s = rr & (S - 1); }

  int d = threadIdx.x;
  __shared__ float red[HD];
  __shared__ float nrm[HD];
  float v = ptr[d];
  red[d] = v * v;
  __syncthreads();
  for (int o = 64; o > 0; o >>= 1) {
    if (d < o) red[d] += red[d + o];
    __syncthreads();
  }
  float inv = rsqrtf(red[0] / (float)HD + EPSR);
  float nv = v * inv * w[d];
  nrm[d] = nv;
  __syncthreads();
  float other = nrm[d ^ 64];
  float rot = (d < 64) ? -other : other;
  float c  = cosT[(size_t)s * HD + d];
  float sn = sinT[(size_t)s * HD + d];
  ptr[d] = nv * c + rot * sn;
}

// ============ wave-per-row top-k + masked softmax + sparse PV (no __syncthreads) ======
#define MAXK 256
#define WPB 4

__device__ __forceinline__ float key_to_float(unsigned u) {
  unsigned f = (u & 0x80000000u) ? (u & 0x7FFFFFFFu) : ~u;
  return __uint_as_float(f);
}

__global__ __launch_bounds__(256) void topk_pv_w(
    const float* __restrict__ score, size_t score_hs,
    const float* __restrict__ vb, float* __restrict__ attnF, int head0)
{
  int z = blockIdx.z;
  int h = head0 + z;
  int w = threadIdx.x >> 6, lane = threadIdx.x & 63;
  int q = blockIdx.x * WPB + w;
  const float* srow = score + (size_t)z * score_hs + (size_t)q * S;
  const float* V = vb + (size_t)(h >> 1) * (S * HD);

  __shared__ unsigned hist[WPB][256];
  __shared__ float wL[WPB][MAXK];
  __shared__ unsigned short idxL[WPB][MAXK];
  __shared__ unsigned cntS[WPB];

  // ---- load 32 keys/lane into registers, monotone map, wave max ----
  unsigned key[32];
  unsigned lmax = 0;
#pragma unroll
  for (int i4 = 0; i4 < 8; i4++) {
    float4 v = *(const float4*)&srow[i4 * 256 + lane * 4];
    unsigned u0 = __float_as_uint(v.x), u1 = __float_as_uint(v.y);
    unsigned u2 = __float_as_uint(v.z), u3 = __float_as_uint(v.w);
    u0 = (u0 & 0x80000000u) ? ~u0 : (u0 | 0x80000000u);
    u1 = (u1 & 0x80000000u) ? ~u1 : (u1 | 0x80000000u);
    u2 = (u2 & 0x80000000u) ? ~u2 : (u2 | 0x80000000u);
    u3 = (u3 & 0x80000000u) ? ~u3 : (u3 | 0x80000000u);
    key[i4 * 4 + 0] = u0; key[i4 * 4 + 1] = u1;
    key[i4 * 4 + 2] = u2; key[i4 * 4 + 3] = u3;
    lmax = max(lmax, max(max(u0, u1), max(u2, u3)));
  }
#pragma unroll
  for (int o = 1; o < 64; o <<= 1) lmax = max(lmax, __shfl_xor(lmax, o));
  float mf = key_to_float(lmax);
  if (lane == 0) cntS[w] = 0;

  // ---- 4 radix rounds (wave-local, keys in registers) ----
  unsigned t = TOPK;
  unsigned prefix = 0;
#pragma unroll
  for (int round = 0; round < 4; round++) {
    int shift = 24 - round * 8;
    // clear wave-private histogram
#pragma unroll
    for (int b = 0; b < 4; b++) hist[w][lane * 4 + b] = 0;
    __builtin_amdgcn_wave_barrier();
    // histogram of current byte over keys matching the prefix so far
    unsigned pmask = (round == 0) ? 0u : (0xFFFFFFFFu << (shift + 8));
#pragma unroll
    for (int i = 0; i < 32; i++) {
      if ((key[i] & pmask) == (prefix & pmask))
        atomicAdd(&hist[w][(key[i] >> shift) & 255u], 1u);
    }
    __builtin_amdgcn_wave_barrier();
    // per-lane 4-bin suffix + wave suffix-scan
    unsigned h0 = hist[w][lane * 4 + 0], h1 = hist[w][lane * 4 + 1];
    unsigned h2 = hist[w][lane * 4 + 2], h3 = hist[w][lane * 4 + 3];
    unsigned s3 = h3, s2 = h2 + s3, s1 = h1 + s2, s0 = h0 + s1;
    unsigned tot = s0, run = tot;
#pragma unroll
    for (int o = 1; o < 64; o <<= 1) {
      unsigned y = __shfl_down(run, o);
      if (lane + o < 64) run += y;
    }
    unsigned above = run - tot;   // sum over bins strictly greater than lane*4+3
    unsigned sfx[4] = { s0 + above, s1 + above, s2 + above, s3 + above };
    unsigned nxt[4] = { sfx[1], sfx[2], sfx[3], above };
    unsigned pack = 0;
#pragma unroll
    for (int b = 0; b < 4; b++) {
      if (sfx[b] >= t && nxt[b] < t)
        pack = (((unsigned)(lane * 4 + b)) << 16) | (t - nxt[b]);
    }
#pragma unroll
    for (int o = 1; o < 64; o <<= 1) pack = max(pack, __shfl_xor(pack, o));
    unsigned bin = pack >> 16;
    t = pack & 0xFFFFu;
    prefix |= bin << shift;
  }
  unsigned thr = prefix;   // bit pattern of the 40th-largest key

  // ---- gather kept entries (>= thr, plus diagonal), softmax weights ----
  float zl = 0.f;
#pragma unroll
  for (int i = 0; i < 32; i++) {
    int j = (i >> 2) * 256 + lane * 4 + (i & 3);
    unsigned u = key[i];
    if (u >= thr || j == q) {
      float sf = key_to_float(u);
      float wv = expf(sf - mf);
      zl += wv;
      unsigned p = atomicAdd(&cntS[w], 1u);
      if (p < MAXK) { wL[w][p] = wv; idxL[w][p] = (unsigned short)j; }
    }
  }
  __builtin_amdgcn_wave_barrier();
#pragma unroll
  for (int o = 1; o < 64; o <<= 1) zl += __shfl_xor(zl, o);
  float Zinv = 1.0f / zl;
  int cnt = (int)min(cntS[w], (unsigned)MAXK);

  // ---- sparse PV: lane covers dims {lane, lane+64} ----
  float o0 = 0.f, o1 = 0.f;
  for (int p = 0; p < cnt; p++) {
    float wv = wL[w][p];
    int idx = idxL[w][p];
    const float* vr = &V[(size_t)idx * HD];
    o0 = fmaf(wv, vr[lane], o0);
    o1 = fmaf(wv, vr[lane + 64], o1);
  }
  size_t oi = (size_t)q * 2048 + (size_t)h * HD + lane;
  attnF[oi] = o0 * Zinv;
  attnF[oi + 64] = o1 * Zinv;
}

// ============ fp32 -> f16 hi/lo split ============
__global__ __launch_bounds__(256) void cvt_split(
    const float* __restrict__ src, _Float16* __restrict__ hi, _Float16* __restrict__ lo, int n)
{
  int i = (blockIdx.x * 256 + threadIdx.x) * 4;
  if (i >= n) return;
  float4 v = *(const float4*)&src[i];
  f16x4 h, l;
  h.x = (_Float16)v.x; l.x = (_Float16)(v.x - (float)h.x);
  h.y = (_Float16)v.y; l.y = (_Float16)(v.y - (float)h.y);
  h.z = (_Float16)v.z; l.z = (_Float16)(v.z - (float)h.z);
  h.w = (_Float16)v.w; l.w = (_Float16)(v.w - (float)h.w);
  *(f16x4*)&hi[i] = h;
  *(f16x4*)&lo[i] = l;
}

// ============ MFMA split-f16 GEMM, for out-projection (post-decision) ============
#define TM 128
#define TN 128
#define TBK 32

template<int TERMS>
__global__ __launch_bounds__(256) void gemm3(
    const _Float16* __restrict__ Ahi, const _Float16* __restrict__ Alo, int lda, size_t a_hs,
    const _Float16* __restrict__ Bhi, const _Float16* __restrict__ Blo, int ldb, size_t b_hs, int b_div,
    float* __restrict__ C, int ldc, size_t c_hs,
    int K, float alpha, int head0)
{
  int h = head0 + blockIdx.z;
  Ahi += (size_t)h * a_hs; Alo += (size_t)h * a_hs;
  Bhi += (size_t)(h / b_div) * b_hs; Blo += (size_t)(h / b_div) * b_hs;
  C += (size_t)blockIdx.z * c_hs;

  __shared__ __align__(16) _Float16 sAh[TM * TBK];
  __shared__ __align__(16) _Float16 sAl[TM * TBK];
  __shared__ __align__(16) _Float16 sBh[TN * TBK];
  __shared__ __align__(16) _Float16 sBl[TN * TBK];

  int tid = threadIdx.x;
  int lane = tid & 63, w = tid >> 6;
  int wrow = w & 1, wcol = w >> 1;
  int m0 = blockIdx.x * TM, n0 = blockIdx.y * TN;

  f32x4 acc[4][4] = {};

  int fr = lane & 15;
  int fk = (lane >> 4) * 8;

  int chunk0 = w * 128 + lane;
  int chunk1 = chunk0 + 64;
  int r0 = chunk0 >> 2, c0 = (chunk0 & 3) * 8;
  int r1 = chunk1 >> 2, c1 = (chunk1 & 3) * 8;

  for (int k0 = 0; k0 < K; k0 += TBK) {
    {
      size_t ga0 = (size_t)(m0 + r0) * lda + k0 + c0;
      size_t ga1 = (size_t)(m0 + r1) * lda + k0 + c1;
      size_t gb0 = (size_t)(n0 + r0) * ldb + k0 + c0;
      size_t gb1 = (size_t)(n0 + r1) * ldb + k0 + c1;
      __builtin_amdgcn_global_load_lds(GLB(Ahi + ga0), LDSP(sAh + chunk0 * 8), 16, 0, 0);
      __builtin_amdgcn_global_load_lds(GLB(Ahi + ga1), LDSP(sAh + chunk1 * 8), 16, 0, 0);
      __builtin_amdgcn_global_load_lds(GLB(Alo + ga0), LDSP(sAl + chunk0 * 8), 16, 0, 0);
      __builtin_amdgcn_global_load_lds(GLB(Alo + ga1), LDSP(sAl + chunk1 * 8), 16, 0, 0);
      __builtin_amdgcn_global_load_lds(GLB(Bhi + gb0), LDSP(sBh + chunk0 * 8), 16, 0, 0);
      __builtin_amdgcn_global_load_lds(GLB(Bhi + gb1), LDSP(sBh + chunk1 * 8), 16, 0, 0);
      __builtin_amdgcn_global_load_lds(GLB(Blo + gb0), LDSP(sBl + chunk0 * 8), 16, 0, 0);
      __builtin_amdgcn_global_load_lds(GLB(Blo + gb1), LDSP(sBl + chunk1 * 8), 16, 0, 0);
    }
    __builtin_amdgcn_s_waitcnt(0);
    __syncthreads();

    f16x8 ah[4], al[4], bh[4], bl[4];
#pragma unroll
    for (int t = 0; t < 4; t++) {
      int am = wrow * 64 + t * 16 + fr;
      int bn = wcol * 64 + t * 16 + fr;
      ah[t] = *(const f16x8*)&sAh[am * TBK + fk];
      al[t] = *(const f16x8*)&sAl[am * TBK + fk];
      bh[t] = *(const f16x8*)&sBh[bn * TBK + fk];
      bl[t] = *(const f16x8*)&sBl[bn * TBK + fk];
    }
#pragma unroll
    for (int mt = 0; mt < 4; mt++)
#pragma unroll
      for (int nt = 0; nt < 4; nt++) {
        acc[mt][nt] = __builtin_amdgcn_mfma_f32_16x16x32_f16(ah[mt], bh[nt], acc[mt][nt], 0, 0, 0);
        acc[mt][nt] = __builtin_amdgcn_mfma_f32_16x16x32_f16(ah[mt], bl[nt], acc[mt][nt], 0, 0, 0);
        acc[mt][nt] = __builtin_amdgcn_mfma_f32_16x16x32_f16(al[mt], bh[nt], acc[mt][nt], 0, 0, 0);
        if (TERMS == 4)
          acc[mt][nt] = __builtin_amdgcn_mfma_f32_16x16x32_f16(al[mt], bl[nt], acc[mt][nt], 0, 0, 0);
      }
    __syncthreads();
  }

  int cr0 = (lane >> 4) * 4;
  int ccol = lane & 15;
#pragma unroll
  for (int mt = 0; mt < 4; mt++) {
#pragma unroll
    for (int r = 0; r < 4; r++) {
      int row = m0 + wrow * 64 + mt * 16 + cr0 + r;
      float* crow = C + (size_t)row * ldc + n0 + wcol * 64 + ccol;
#pragma unroll
      for (int nt = 0; nt < 4; nt++)
        crow[nt * 16] = alpha * acc[mt][nt][r];
    }
  }
}

// ---------------- launch ----------------
extern "C" void kernel_launch(void* const* d_in, const int* in_sizes, int n_in,
                              void* d_out, int out_size, void* d_ws, size_t ws_size,
                              hipStream_t stream) {
  const float* x    = (const float*)d_in[0];
  const float* cosT = (const float*)d_in[1];
  const float* sinT = (const float*)d_in[2];
  const float* Wq   = (const float*)d_in[3];
  const float* Wk   = (const float*)d_in[4];
  const float* Wv   = (const float*)d_in[5];
  const float* Wo   = (const float*)d_in[6];
  const float* qw   = (const float*)d_in[7];
  const float* kw   = (const float*)d_in[8];
  float* out = (float*)d_out;

  // workspace carve
  char* p = (char*)d_ws;
  float* qb   = (float*)p;        p += (size_t)NH * S * HD * 4;     // 16.8 MB
  float* kb   = (float*)p;        p += (size_t)NKV * S * HD * 4;    //  8.4 MB
  float* vb   = (float*)p;        p += (size_t)NKV * S * HD * 4;    //  8.4 MB
  float* attn = (float*)p;        p += (size_t)S * 2048 * 4;        // 16.8 MB
  _Float16* attnHi = (_Float16*)p; p += (size_t)S * 2048 * 2;       //  8.4 MB
  _Float16* attnLo = (_Float16*)p; p += (size_t)S * 2048 * 2;       //  8.4 MB
  _Float16* WoHi   = (_Float16*)p; p += (size_t)2048 * 2048 * 2;    //  8.4 MB
  _Float16* WoLo   = (_Float16*)p; p += (size_t)2048 * 2048 * 2;    //  8.4 MB
  size_t fixed = (size_t)(p - (char*)d_ws);

  // score slab: as many head-sized (16.8 MB) slots as fit after the fixed carve
  size_t slab = (size_t)S * S * 4;
  size_t avail = ws_size > fixed ? ws_size - fixed : 0;
  int chunkH = (int)(avail / slab);
  float* scoreBuf = (float*)p;
  if (chunkH < 1) {              // fallback: overlay attnHi+attnLo (dead until step 5)
    chunkH = 1;
    scoreBuf = (float*)attnHi;
  }
  if (chunkH > NH) chunkH = NH;
  int nch = (NH + chunkH - 1) / chunkH;
  int per = (NH + nch - 1) / nch;     // balanced chunks

  // 1. QKV projection (fp32, bit-exact ascending-k chain) with scatter
  fgemm<1><<<dim3(16, 32, 1), 256, 0, stream>>>(
      x, D, 0, Wq, Wk, Wv, D, 0, 1,
      nullptr, 0, 0, qb, kb, vb, D, 1.0f, 0);

  // 2. RMSNorm + RoPE (round-1 verbatim)
  rms_rope<<<dim3((NH + NKV) * S), 128, 0, stream>>>(qb, kb, cosT, sinT, qw, kw);

  // 3. split Wo for the MFMA out-projection
  cvt_split<<<4096, 256, 0, stream>>>(Wo, WoHi, WoLo, 2048 * 2048);

  // 4. scores (fp32 bit-exact, x SCALEF) + topk/softmax/PV, head-chunked
  for (int h0 = 0; h0 < NH; h0 += per) {
    int hc = (NH - h0 < per) ? (NH - h0) : per;
    fgemm<0><<<dim3(16, 16, hc), 256, 0, stream>>>(
        qb, HD, (size_t)S * HD, kb, nullptr, nullptr, HD, (size_t)S * HD, 2,
        scoreBuf, S, slab / 4, nullptr, nullptr, nullptr, HD, SCALEF, h0);
    topk_pv_w<<<dim3(S / WPB, 1, hc), 256, 0, stream>>>(scoreBuf, slab / 4, vb, attn, h0);
  }

  // 5. split attn, then MFMA out-projection: out = attn * Wo^T
  cvt_split<<<4096, 256, 0, stream>>>(attn, attnHi, attnLo, 2048 * 2048);
  gemm3<3><<<dim3(16, 16, 1), 256, 0, stream>>>(
      attnHi, attnLo, 2048, 0, WoHi, WoLo, 2048, 0, 1,
      out, 2048, 0, 2048, 1.0f, 0);
}

// Round 7
// 1008.015 us; speedup vs baseline: 2.5039x; 2.5039x over previous
//
#include <hip/hip_runtime.h>
#include <hip/hip_bf16.h>
#include <math.h>

#define S 2048
#define D 2048
#define NH 16
#define NKV 8
#define HD 128
#define TOPK 40
#define EPSR 1e-6f
#define SCALEF 0.08838834764831845f

typedef __attribute__((ext_vector_type(8))) _Float16 f16x8;
typedef __attribute__((ext_vector_type(4))) _Float16 f16x4;
typedef __attribute__((ext_vector_type(4))) float f32x4;

#define GLB(p) ((const __attribute__((address_space(1))) void*)(p))
#define LDSP(p) ((__attribute__((address_space(3))) void*)(p))

// ============ fp32 GEMM, bit-identical accumulation (ascending-k fmaf), double-buffered
// LDS stride 132 (multiple of 4 floats: keeps float4 reads 16B-aligned; 4-way store
// conflicts cost ~7% of iter — measured acceptable; stride 133 broke b128 alignment).
// MODE 0: plain output slab; MODE 1: QKV scatter epilogue
template<int MODE>
__global__ __launch_bounds__(256) void fgemm(
    const float* __restrict__ A, int lda, size_t a_hs,
    const float* __restrict__ B0, const float* __restrict__ B1, const float* __restrict__ B2,
    int ldb, size_t b_hs, int b_div,
    float* __restrict__ C, int ldc, size_t c_hs,
    float* __restrict__ qb, float* __restrict__ kb, float* __restrict__ vb,
    int K, float alpha, int head0)
{
  __shared__ float As[2][32][132];
  __shared__ float Bs[2][32][132];
  int tid = threadIdx.x;
  int tx = tid & 15, ty = tid >> 4;
  int m0 = blockIdx.x * 128, n0 = blockIdx.y * 128;

  const float* Ag = A;
  const float* Bsrc;
  float* Cg = C;
  if (MODE == 0) {
    int h = head0 + blockIdx.z;
    Ag = A + (size_t)h * a_hs;
    Bsrc = B0 + (size_t)(h / b_div) * b_hs + (size_t)n0 * ldb;
    Cg = C + (size_t)blockIdx.z * c_hs;
  } else {
    if (n0 < 2048)      Bsrc = B0 + (size_t)n0 * ldb;
    else if (n0 < 3072) Bsrc = B1 + (size_t)(n0 - 2048) * ldb;
    else                Bsrc = B2 + (size_t)(n0 - 3072) * ldb;
  }

  float acc[8][8] = {};

  int r_[4], c_[4];
#pragma unroll
  for (int i = 0; i < 4; i++) {
    int f4 = tid + i * 256;            // 0..1023
    r_[i] = f4 >> 3;                   // 0..127
    c_[i] = (f4 & 7) * 4;              // 0..28
  }

  float4 avr[4], bvr[4];
  // prologue: tile 0 -> regs -> LDS buf 0
#pragma unroll
  for (int i = 0; i < 4; i++) {
    avr[i] = *(const float4*)&Ag[(size_t)(m0 + r_[i]) * lda + c_[i]];
    bvr[i] = *(const float4*)&Bsrc[(size_t)r_[i] * ldb + c_[i]];
  }
#pragma unroll
  for (int i = 0; i < 4; i++) {
    As[0][c_[i] + 0][r_[i]] = avr[i].x; As[0][c_[i] + 1][r_[i]] = avr[i].y;
    As[0][c_[i] + 2][r_[i]] = avr[i].z; As[0][c_[i] + 3][r_[i]] = avr[i].w;
    Bs[0][c_[i] + 0][r_[i]] = bvr[i].x; Bs[0][c_[i] + 1][r_[i]] = bvr[i].y;
    Bs[0][c_[i] + 2][r_[i]] = bvr[i].z; Bs[0][c_[i] + 3][r_[i]] = bvr[i].w;
  }
  __syncthreads();

  int nIter = K >> 5;
  for (int it = 0; it < nIter; it++) {
    int buf = it & 1;
    bool more = (it + 1) < nIter;
    if (more) {
      int k0 = (it + 1) * 32;
#pragma unroll
      for (int i = 0; i < 4; i++) {
        avr[i] = *(const float4*)&Ag[(size_t)(m0 + r_[i]) * lda + k0 + c_[i]];
        bvr[i] = *(const float4*)&Bsrc[(size_t)r_[i] * ldb + k0 + c_[i]];
      }
    }
    // compute from buf (ascending-k fmaf chain: bit-exact, order unchanged)
    for (int k = 0; k < 32; k++) {
      float a8[8], b8[8];
      *(float4*)&a8[0] = *(const float4*)&As[buf][k][ty * 8];
      *(float4*)&a8[4] = *(const float4*)&As[buf][k][ty * 8 + 4];
      *(float4*)&b8[0] = *(const float4*)&Bs[buf][k][tx * 8];
      *(float4*)&b8[4] = *(const float4*)&Bs[buf][k][tx * 8 + 4];
#pragma unroll
      for (int i = 0; i < 8; i++)
#pragma unroll
        for (int j = 0; j < 8; j++)
          acc[i][j] = fmaf(a8[i], b8[j], acc[i][j]);
    }
    if (more) {
      int nb = buf ^ 1;
#pragma unroll
      for (int i = 0; i < 4; i++) {
        As[nb][c_[i] + 0][r_[i]] = avr[i].x; As[nb][c_[i] + 1][r_[i]] = avr[i].y;
        As[nb][c_[i] + 2][r_[i]] = avr[i].z; As[nb][c_[i] + 3][r_[i]] = avr[i].w;
        Bs[nb][c_[i] + 0][r_[i]] = bvr[i].x; Bs[nb][c_[i] + 1][r_[i]] = bvr[i].y;
        Bs[nb][c_[i] + 2][r_[i]] = bvr[i].z; Bs[nb][c_[i] + 3][r_[i]] = bvr[i].w;
      }
      __syncthreads();
    }
  }

#pragma unroll
  for (int i = 0; i < 8; i++) {
    int m = m0 + ty * 8 + i;
#pragma unroll
    for (int j = 0; j < 8; j++) {
      int n = n0 + tx * 8 + j;
      if (MODE == 0) {
        Cg[(size_t)m * ldc + n] = alpha * acc[i][j];
      } else {
        float val = acc[i][j];
        if (n < 2048) {
          qb[(size_t)(n >> 7) * (S * HD) + (size_t)m * HD + (n & 127)] = val;
        } else if (n < 3072) {
          int nn = n - 2048;
          kb[(size_t)(nn >> 7) * (S * HD) + (size_t)m * HD + (nn & 127)] = val;
        } else {
          int nn = n - 3072;
          vb[(size_t)(nn >> 7) * (S * HD) + (size_t)m * HD + (nn & 127)] = val;
        }
      }
    }
  }
}

// ============ round-1 rms_rope VERBATIM (bit-exact decision path) ============
__global__ __launch_bounds__(128) void rms_rope(
    float* __restrict__ qb, float* __restrict__ kb,
    const float* __restrict__ cosT, const float* __restrict__ sinT,
    const float* __restrict__ qw, const float* __restrict__ kw)
{
  int r = blockIdx.x;
  float* ptr; const float* w; int s;
  if (r < NH * S) { ptr = qb + (size_t)r * HD; w = qw; s = r & (S - 1); }
  else { int rr = r - NH * S; ptr = kb + (size_t)rr * HD; w = kw; s = rr & (S - 1); }

  int d = threadIdx.x;
  __shared__ float red[HD];
  __shared__ float nrm[HD];
  float v = ptr[d];
  red[d] = v * v;
  __syncthreads();
  for (int o = 64; o > 0; o >>= 1) {
    if (d < o) red[d] += red[d + o];
    __syncthreads();
  }
  float inv = rsqrtf(red[0] / (float)HD + EPSR);
  float nv = v * inv * w[d];
  nrm[d] = nv;
  __syncthreads();
  float other = nrm[d ^ 64];
  float rot = (d < 64) ? -other : other;
  float c  = cosT[(size_t)s * HD + d];
  float sn = sinT[(size_t)s * HD + d];
  ptr[d] = nv * c + rot * sn;
}

// ============ wave-per-row top-k + masked softmax + sparse PV (no __syncthreads) ======
#define MAXK 256
#define WPB 4

__device__ __forceinline__ float key_to_float(unsigned u) {
  unsigned f = (u & 0x80000000u) ? (u & 0x7FFFFFFFu) : ~u;
  return __uint_as_float(f);
}

__global__ __launch_bounds__(256) void topk_pv_w(
    const float* __restrict__ score, size_t score_hs,
    const float* __restrict__ vb, float* __restrict__ attnF, int head0)
{
  int z = blockIdx.z;
  int h = head0 + z;
  int w = threadIdx.x >> 6, lane = threadIdx.x & 63;
  int q = blockIdx.x * WPB + w;
  const float* srow = score + (size_t)z * score_hs + (size_t)q * S;
  const float* V = vb + (size_t)(h >> 1) * (S * HD);

  __shared__ unsigned hist[WPB][256];
  __shared__ float wL[WPB][MAXK];
  __shared__ unsigned short idxL[WPB][MAXK];
  __shared__ unsigned cntS[WPB];

  // ---- load 32 keys/lane into registers, monotone map, wave max ----
  unsigned key[32];
  unsigned lmax = 0;
#pragma unroll
  for (int i4 = 0; i4 < 8; i4++) {
    float4 v = *(const float4*)&srow[i4 * 256 + lane * 4];
    unsigned u0 = __float_as_uint(v.x), u1 = __float_as_uint(v.y);
    unsigned u2 = __float_as_uint(v.z), u3 = __float_as_uint(v.w);
    u0 = (u0 & 0x80000000u) ? ~u0 : (u0 | 0x80000000u);
    u1 = (u1 & 0x80000000u) ? ~u1 : (u1 | 0x80000000u);
    u2 = (u2 & 0x80000000u) ? ~u2 : (u2 | 0x80000000u);
    u3 = (u3 & 0x80000000u) ? ~u3 : (u3 | 0x80000000u);
    key[i4 * 4 + 0] = u0; key[i4 * 4 + 1] = u1;
    key[i4 * 4 + 2] = u2; key[i4 * 4 + 3] = u3;
    lmax = max(lmax, max(max(u0, u1), max(u2, u3)));
  }
#pragma unroll
  for (int o = 1; o < 64; o <<= 1) lmax = max(lmax, __shfl_xor(lmax, o));
  float mf = key_to_float(lmax);
  if (lane == 0) cntS[w] = 0;

  // ---- 4 radix rounds (wave-local, keys in registers) ----
  unsigned t = TOPK;
  unsigned prefix = 0;
#pragma unroll
  for (int round = 0; round < 4; round++) {
    int shift = 24 - round * 8;
#pragma unroll
    for (int b = 0; b < 4; b++) hist[w][lane * 4 + b] = 0;
    __builtin_amdgcn_wave_barrier();
    unsigned pmask = (round == 0) ? 0u : (0xFFFFFFFFu << (shift + 8));
#pragma unroll
    for (int i = 0; i < 32; i++) {
      if ((key[i] & pmask) == (prefix & pmask))
        atomicAdd(&hist[w][(key[i] >> shift) & 255u], 1u);
    }
    __builtin_amdgcn_wave_barrier();
    unsigned h0 = hist[w][lane * 4 + 0], h1 = hist[w][lane * 4 + 1];
    unsigned h2 = hist[w][lane * 4 + 2], h3 = hist[w][lane * 4 + 3];
    unsigned s3 = h3, s2 = h2 + s3, s1 = h1 + s2, s0 = h0 + s1;
    unsigned tot = s0, run = tot;
#pragma unroll
    for (int o = 1; o < 64; o <<= 1) {
      unsigned y = __shfl_down(run, o);
      if (lane + o < 64) run += y;
    }
    unsigned above = run - tot;
    unsigned sfx[4] = { s0 + above, s1 + above, s2 + above, s3 + above };
    unsigned nxt[4] = { sfx[1], sfx[2], sfx[3], above };
    unsigned pack = 0;
#pragma unroll
    for (int b = 0; b < 4; b++) {
      if (sfx[b] >= t && nxt[b] < t)
        pack = (((unsigned)(lane * 4 + b)) << 16) | (t - nxt[b]);
    }
#pragma unroll
    for (int o = 1; o < 64; o <<= 1) pack = max(pack, __shfl_xor(pack, o));
    unsigned bin = pack >> 16;
    t = pack & 0xFFFFu;
    prefix |= bin << shift;
  }
  unsigned thr = prefix;

  // ---- gather kept entries (>= thr, plus diagonal), softmax weights ----
  float zl = 0.f;
#pragma unroll
  for (int i = 0; i < 32; i++) {
    int j = (i >> 2) * 256 + lane * 4 + (i & 3);
    unsigned u = key[i];
    if (u >= thr || j == q) {
      float sf = key_to_float(u);
      float wv = expf(sf - mf);
      zl += wv;
      unsigned p = atomicAdd(&cntS[w], 1u);
      if (p < MAXK) { wL[w][p] = wv; idxL[w][p] = (unsigned short)j; }
    }
  }
  __builtin_amdgcn_wave_barrier();
#pragma unroll
  for (int o = 1; o < 64; o <<= 1) zl += __shfl_xor(zl, o);
  float Zinv = 1.0f / zl;
  int cnt = (int)min(cntS[w], (unsigned)MAXK);

  // ---- sparse PV: lane covers dims {lane, lane+64} ----
  float o0 = 0.f, o1 = 0.f;
  for (int p = 0; p < cnt; p++) {
    float wv = wL[w][p];
    int idx = idxL[w][p];
    const float* vr = &V[(size_t)idx * HD];
    o0 = fmaf(wv, vr[lane], o0);
    o1 = fmaf(wv, vr[lane + 64], o1);
  }
  size_t oi = (size_t)q * 2048 + (size_t)h * HD + lane;
  attnF[oi] = o0 * Zinv;
  attnF[oi + 64] = o1 * Zinv;
}

// ============ fp32 -> f16 hi/lo split ============
__global__ __launch_bounds__(256) void cvt_split(
    const float* __restrict__ src, _Float16* __restrict__ hi, _Float16* __restrict__ lo, int n)
{
  int i = (blockIdx.x * 256 + threadIdx.x) * 4;
  if (i >= n) return;
  float4 v = *(const float4*)&src[i];
  f16x4 h, l;
  h.x = (_Float16)v.x; l.x = (_Float16)(v.x - (float)h.x);
  h.y = (_Float16)v.y; l.y = (_Float16)(v.y - (float)h.y);
  h.z = (_Float16)v.z; l.z = (_Float16)(v.z - (float)h.z);
  h.w = (_Float16)v.w; l.w = (_Float16)(v.w - (float)h.w);
  *(f16x4*)&hi[i] = h;
  *(f16x4*)&lo[i] = l;
}

// ============ MFMA split-f16 GEMM, for out-projection (post-decision) ============
#define TM 128
#define TN 128
#define TBK 32

template<int TERMS>
__global__ __launch_bounds__(256) void gemm3(
    const _Float16* __restrict__ Ahi, const _Float16* __restrict__ Alo, int lda, size_t a_hs,
    const _Float16* __restrict__ Bhi, const _Float16* __restrict__ Blo, int ldb, size_t b_hs, int b_div,
    float* __restrict__ C, int ldc, size_t c_hs,
    int K, float alpha, int head0)
{
  int h = head0 + blockIdx.z;
  Ahi += (size_t)h * a_hs; Alo += (size_t)h * a_hs;
  Bhi += (size_t)(h / b_div) * b_hs; Blo += (size_t)(h / b_div) * b_hs;
  C += (size_t)blockIdx.z * c_hs;

  __shared__ __align__(16) _Float16 sAh[TM * TBK];
  __shared__ __align__(16) _Float16 sAl[TM * TBK];
  __shared__ __align__(16) _Float16 sBh[TN * TBK];
  __shared__ __align__(16) _Float16 sBl[TN * TBK];

  int tid = threadIdx.x;
  int lane = tid & 63, w = tid >> 6;
  int wrow = w & 1, wcol = w >> 1;
  int m0 = blockIdx.x * TM, n0 = blockIdx.y * TN;

  f32x4 acc[4][4] = {};

  int fr = lane & 15;
  int fk = (lane >> 4) * 8;

  int chunk0 = w * 128 + lane;
  int chunk1 = chunk0 + 64;
  int r0 = chunk0 >> 2, c0 = (chunk0 & 3) * 8;
  int r1 = chunk1 >> 2, c1 = (chunk1 & 3) * 8;

  for (int k0 = 0; k0 < K; k0 += TBK) {
    {
      size_t ga0 = (size_t)(m0 + r0) * lda + k0 + c0;
      size_t ga1 = (size_t)(m0 + r1) * lda + k0 + c1;
      size_t gb0 = (size_t)(n0 + r0) * ldb + k0 + c0;
      size_t gb1 = (size_t)(n0 + r1) * ldb + k0 + c1;
      __builtin_amdgcn_global_load_lds(GLB(Ahi + ga0), LDSP(sAh + chunk0 * 8), 16, 0, 0);
      __builtin_amdgcn_global_load_lds(GLB(Ahi + ga1), LDSP(sAh + chunk1 * 8), 16, 0, 0);
      __builtin_amdgcn_global_load_lds(GLB(Alo + ga0), LDSP(sAl + chunk0 * 8), 16, 0, 0);
      __builtin_amdgcn_global_load_lds(GLB(Alo + ga1), LDSP(sAl + chunk1 * 8), 16, 0, 0);
      __builtin_amdgcn_global_load_lds(GLB(Bhi + gb0), LDSP(sBh + chunk0 * 8), 16, 0, 0);
      __builtin_amdgcn_global_load_lds(GLB(Bhi + gb1), LDSP(sBh + chunk1 * 8), 16, 0, 0);
      __builtin_amdgcn_global_load_lds(GLB(Blo + gb0), LDSP(sBl + chunk0 * 8), 16, 0, 0);
      __builtin_amdgcn_global_load_lds(GLB(Blo + gb1), LDSP(sBl + chunk1 * 8), 16, 0, 0);
    }
    __builtin_amdgcn_s_waitcnt(0);
    __syncthreads();

    f16x8 ah[4], al[4], bh[4], bl[4];
#pragma unroll
    for (int t = 0; t < 4; t++) {
      int am = wrow * 64 + t * 16 + fr;
      int bn = wcol * 64 + t * 16 + fr;
      ah[t] = *(const f16x8*)&sAh[am * TBK + fk];
      al[t] = *(const f16x8*)&sAl[am * TBK + fk];
      bh[t] = *(const f16x8*)&sBh[bn * TBK + fk];
      bl[t] = *(const f16x8*)&sBl[bn * TBK + fk];
    }
#pragma unroll
    for (int mt = 0; mt < 4; mt++)
#pragma unroll
      for (int nt = 0; nt < 4; nt++) {
        acc[mt][nt] = __builtin_amdgcn_mfma_f32_16x16x32_f16(ah[mt], bh[nt], acc[mt][nt], 0, 0, 0);
        acc[mt][nt] = __builtin_amdgcn_mfma_f32_16x16x32_f16(ah[mt], bl[nt], acc[mt][nt], 0, 0, 0);
        acc[mt][nt] = __builtin_amdgcn_mfma_f32_16x16x32_f16(al[mt], bh[nt], acc[mt][nt], 0, 0, 0);
        if (TERMS == 4)
          acc[mt][nt] = __builtin_amdgcn_mfma_f32_16x16x32_f16(al[mt], bl[nt], acc[mt][nt], 0, 0, 0);
      }
    __syncthreads();
  }

  int cr0 = (lane >> 4) * 4;
  int ccol = lane & 15;
#pragma unroll
  for (int mt = 0; mt < 4; mt++) {
#pragma unroll
    for (int r = 0; r < 4; r++) {
      int row = m0 + wrow * 64 + mt * 16 + cr0 + r;
      float* crow = C + (size_t)row * ldc + n0 + wcol * 64 + ccol;
#pragma unroll
      for (int nt = 0; nt < 4; nt++)
        crow[nt * 16] = alpha * acc[mt][nt][r];
    }
  }
}

// ---------------- launch ----------------
extern "C" void kernel_launch(void* const* d_in, const int* in_sizes, int n_in,
                              void* d_out, int out_size, void* d_ws, size_t ws_size,
                              hipStream_t stream) {
  const float* x    = (const float*)d_in[0];
  const float* cosT = (const float*)d_in[1];
  const float* sinT = (const float*)d_in[2];
  const float* Wq   = (const float*)d_in[3];
  const float* Wk   = (const float*)d_in[4];
  const float* Wv   = (const float*)d_in[5];
  const float* Wo   = (const float*)d_in[6];
  const float* qw   = (const float*)d_in[7];
  const float* kw   = (const float*)d_in[8];
  float* out = (float*)d_out;

  // workspace carve
  char* p = (char*)d_ws;
  float* qb   = (float*)p;        p += (size_t)NH * S * HD * 4;     // 16.8 MB
  float* kb   = (float*)p;        p += (size_t)NKV * S * HD * 4;    //  8.4 MB
  float* vb   = (float*)p;        p += (size_t)NKV * S * HD * 4;    //  8.4 MB
  float* attn = (float*)p;        p += (size_t)S * 2048 * 4;        // 16.8 MB
  _Float16* attnHi = (_Float16*)p; p += (size_t)S * 2048 * 2;       //  8.4 MB
  _Float16* attnLo = (_Float16*)p; p += (size_t)S * 2048 * 2;       //  8.4 MB
  _Float16* WoHi   = (_Float16*)p; p += (size_t)2048 * 2048 * 2;    //  8.4 MB
  _Float16* WoLo   = (_Float16*)p; p += (size_t)2048 * 2048 * 2;    //  8.4 MB
  size_t fixed = (size_t)(p - (char*)d_ws);

  // score slab: as many head-sized (16.8 MB) slots as fit after the fixed carve
  size_t slab = (size_t)S * S * 4;
  size_t avail = ws_size > fixed ? ws_size - fixed : 0;
  int chunkH = (int)(avail / slab);
  float* scoreBuf = (float*)p;
  if (chunkH < 1) {              // fallback: overlay attnHi+attnLo (dead until step 5)
    chunkH = 1;
    scoreBuf = (float*)attnHi;
  }
  if (chunkH > NH) chunkH = NH;
  int nch = (NH + chunkH - 1) / chunkH;
  int per = (NH + nch - 1) / nch;     // balanced chunks

  // 1. QKV projection (fp32, bit-exact ascending-k chain) with scatter
  fgemm<1><<<dim3(16, 32, 1), 256, 0, stream>>>(
      x, D, 0, Wq, Wk, Wv, D, 0, 1,
      nullptr, 0, 0, qb, kb, vb, D, 1.0f, 0);

  // 2. RMSNorm + RoPE (round-1 verbatim)
  rms_rope<<<dim3((NH + NKV) * S), 128, 0, stream>>>(qb, kb, cosT, sinT, qw, kw);

  // 3. split Wo for the MFMA out-projection
  cvt_split<<<4096, 256, 0, stream>>>(Wo, WoHi, WoLo, 2048 * 2048);

  // 4. scores (fp32 bit-exact, x SCALEF) + topk/softmax/PV, head-chunked
  for (int h0 = 0; h0 < NH; h0 += per) {
    int hc = (NH - h0 < per) ? (NH - h0) : per;
    fgemm<0><<<dim3(16, 16, hc), 256, 0, stream>>>(
        qb, HD, (size_t)S * HD, kb, nullptr, nullptr, HD, (size_t)S * HD, 2,
        scoreBuf, S, slab / 4, nullptr, nullptr, nullptr, HD, SCALEF, h0);
    topk_pv_w<<<dim3(S / WPB, 1, hc), 256, 0, stream>>>(scoreBuf, slab / 4, vb, attn, h0);
  }

  // 5. split attn, then MFMA out-projection: out = attn * Wo^T
  cvt_split<<<4096, 256, 0, stream>>>(attn, attnHi, attnLo, 2048 * 2048);
  gemm3<3><<<dim3(16, 16, 1), 256, 0, stream>>>(
      attnHi, attnLo, 2048, 0, WoHi, WoLo, 2048, 0, 1,
      out, 2048, 0, 2048, 1.0f, 0);
}